// Round 10
// baseline (364.970 us; speedup 1.0000x reference)
//
#include <hip/hip_runtime.h>

// SupConLoss, B=4096 D=256 L=20, T=0.07 — SINGLE persistent dispatch.
// Phases (manual grid barrier, 256 blocks = 256 CUs, 1 block/CU co-resident):
//  0: zero Wt/ACC/MP/EP (poison-safe MAGIC-flag handshake zeroes the barrier ctr first)
//  1: F@F^T row-reduce GEMM per block (round-8 body: 512x128 tile, B-panel LDS,
//     A streamed, per-row atomicMax(max)/atomicAdd(stabilized expsum)) + CV publish;
//     then Wt one-hot accumulation + label counts as per-block tail jobs
//  2: per-row val = lp+m bucketed into per-(l,v) accumulators (O(B*L), factorized final:
//     sum_i masked_mean = (INVT*||Wt[l,v]||^2 - sum_i c_i)/(cnt-1))
//  3: block 0: ||Wt||^2 norms + final scalar.
// All cross-phase data moves via agent-scope atomics (cross-XCD L2 safety).

#define INVT 14.285714285714286f
#define MAGIC 0x5EC7BA11u

// ws layout (bytes)
#define BAR_OFF  0x000000u  // u32 ctr, u32 flag
#define CNT_OFF  0x004000u  // int [20][5]
#define WT_OFF   0x010000u  // f32 [100][256]    (zeroed in phase 0)
#define ACC_OFF  0x029000u  // f32 LPM[100], C[100] (zeroed in phase 0)
#define MP_OFF   0x02A000u  // u32 [4096] ordered-float row max (zeroed)
#define EP_OFF   0x02E000u  // f32 [4096] row expsum (zeroed)      [zero region ends 0x32000]
#define CV_OFF   0x032000u  // f32 [4096] c_i (S units), written by bn==0 GEMM blocks

typedef __bf16 bf16x8 __attribute__((ext_vector_type(8)));
typedef float f32x4 __attribute__((ext_vector_type(4)));

struct __align__(16) U4 { unsigned int x, y, z, w; };

__device__ __forceinline__ U4 pack8(float4 a, float4 b) {
  bf16x8 v;
  v[0] = (__bf16)a.x; v[1] = (__bf16)a.y; v[2] = (__bf16)a.z; v[3] = (__bf16)a.w;
  v[4] = (__bf16)b.x; v[5] = (__bf16)b.y; v[6] = (__bf16)b.z; v[7] = (__bf16)b.w;
  return __builtin_bit_cast(U4, v);
}

__device__ __forceinline__ unsigned int ordf(float x) {  // monotone float->uint
  unsigned int u = __float_as_uint(x);
  return (u & 0x80000000u) ? ~u : (u | 0x80000000u);
}
__device__ __forceinline__ float ordinv(unsigned int o) {
  return __uint_as_float((o & 0x80000000u) ? (o & 0x7FFFFFFFu) : ~o);
}

__device__ __forceinline__ void stu(unsigned* p, unsigned v) {
  __hip_atomic_store(p, v, __ATOMIC_RELAXED, __HIP_MEMORY_SCOPE_AGENT);
}
__device__ __forceinline__ void stf(float* p, float v) {
  __hip_atomic_store(p, v, __ATOMIC_RELAXED, __HIP_MEMORY_SCOPE_AGENT);
}
__device__ __forceinline__ float ldf(const float* p) {
  return __hip_atomic_load(p, __ATOMIC_RELAXED, __HIP_MEMORY_SCOPE_AGENT);
}
__device__ __forceinline__ unsigned ldu(const unsigned* p) {
  return __hip_atomic_load(p, __ATOMIC_RELAXED, __HIP_MEMORY_SCOPE_AGENT);
}
__device__ __forceinline__ int ldi(const int* p) {
  return __hip_atomic_load(p, __ATOMIC_RELAXED, __HIP_MEMORY_SCOPE_AGENT);
}

__device__ __forceinline__ void gsync(unsigned* ctr, unsigned target) {
  __syncthreads();
  if (threadIdx.x == 0) {
    __threadfence();  // release all prior writes device-wide
    __hip_atomic_fetch_add(ctr, 1u, __ATOMIC_ACQ_REL, __HIP_MEMORY_SCOPE_AGENT);
    while (__hip_atomic_load(ctr, __ATOMIC_ACQUIRE, __HIP_MEMORY_SCOPE_AGENT) < target)
      __builtin_amdgcn_s_sleep(2);
  }
  __syncthreads();
}

__global__ __launch_bounds__(512, 2) void k_mega(const float* __restrict__ F,
                                                 const int* __restrict__ lab,
                                                 unsigned char* __restrict__ ws,
                                                 float* __restrict__ out) {
  __shared__ unsigned char smem[67584];  // 64K B-panel | 2K scv (unioned per phase)
  const int bid = blockIdx.x, t = threadIdx.x;
  unsigned* ctr = (unsigned*)(ws + BAR_OFF);

  // ---- poison-safe handshake: block 0 zeroes ctr, publishes MAGIC flag ----
  if (bid == 0 && t == 0) {
    __hip_atomic_store(ctr, 0u, __ATOMIC_RELAXED, __HIP_MEMORY_SCOPE_AGENT);
    __hip_atomic_store(ctr + 1, MAGIC, __ATOMIC_RELEASE, __HIP_MEMORY_SCOPE_AGENT);
  }
  if (t == 0) {
    while (__hip_atomic_load(ctr + 1, __ATOMIC_ACQUIRE, __HIP_MEMORY_SCOPE_AGENT) != MAGIC)
      __builtin_amdgcn_s_sleep(2);
  }
  __syncthreads();

  // ---- phase 0: zero [WT, ACC, MP, EP) = 0x22000 bytes ----
  {
    unsigned* z = (unsigned*)(ws + WT_OFF);
    const int n = 0x22000 / 4;
    for (int k = bid * 512 + t; k < n; k += 256 * 512) stu(z + k, 0u);
  }
  gsync(ctr, 256);

  // ---- phase 1a: GEMM tile (every block owns one 512x128 tile) ----
  {
    const int w = t >> 6, l = t & 63;
    const int lr = l & 15, lg = l >> 4;
    const int r = bid & 7, s = bid >> 3;          // 2-D XCD partition (perf-only)
    const int bm = ((r & 3) << 1) | (s & 1);
    const int bn = ((r >> 2) << 4) | (s >> 1);
    const int rowbase = bm * 512 + w * 64;
    const int colb = bn * 128;
    // stage B-panel rows [colb..colb+128): fp32 -> bf16 -> swizzled LDS
    {
      const int srow = t >> 2, q = t & 3;
      const float* src = F + (size_t)(colb + srow) * 256 + q * 64;
      #pragma unroll
      for (int i = 0; i < 8; ++i) {
        float4 f0 = *(const float4*)(src + i * 8);
        float4 f1 = *(const float4*)(src + i * 8 + 4);
        const int kb = q * 128 + i * 16;
        *(U4*)(smem + srow * 512 + (kb ^ ((srow & 7) << 4))) = pack8(f0, f1);
      }
    }
    __syncthreads();
    unsigned int* MP = (unsigned int*)(ws + MP_OFF);
    float* EP = (float*)(ws + EP_OFF);
    float* CV = (float*)(ws + CV_OFF);
    float* scv = (float*)(smem + 65536);          // [8 waves][64 rows] c_i (S units)
    const float* arow0 = F + (size_t)(rowbase + lr) * 256 + lg * 8;
    float ssq[4] = {0.f, 0.f, 0.f, 0.f};
    #pragma unroll 1
    for (int tile = 0; tile < 2; ++tile) {
      f32x4 acc[4][4] = {};
      #pragma unroll 1
      for (int kk = 0; kk < 8; ++kk) {
        bf16x8 afr[4];
        #pragma unroll
        for (int mi = 0; mi < 4; ++mi) {
          const float* ap = arow0 + mi * 16 * 256 + kk * 32;
          float4 a0 = *(const float4*)(ap);
          float4 a1 = *(const float4*)(ap + 4);
          if (tile == 0)
            ssq[mi] += a0.x * a0.x + a0.y * a0.y + a0.z * a0.z + a0.w * a0.w
                     + a1.x * a1.x + a1.y * a1.y + a1.z * a1.z + a1.w * a1.w;
          afr[mi] = __builtin_bit_cast(bf16x8, pack8(a0, a1));
        }
        bf16x8 bfr[4];
        #pragma unroll
        for (int n = 0; n < 4; ++n) {
          const int brow = tile * 64 + n * 16 + lr;
          const int kb = kk * 64 + lg * 16;
          bfr[n] = __builtin_bit_cast(bf16x8,
              *(const U4*)(smem + brow * 512 + (kb ^ ((brow & 7) << 4))));
        }
        #pragma unroll
        for (int mi = 0; mi < 4; ++mi)
          #pragma unroll
          for (int n = 0; n < 4; ++n)
            acc[mi][n] = __builtin_amdgcn_mfma_f32_16x16x32_bf16(afr[mi], bfr[n], acc[mi][n], 0, 0, 0);
      }
      if (tile == 0) {
        // finish per-row sumsq: lanes {lr, lr+16, lr+32, lr+48} hold partials of row mi*16+lr
        #pragma unroll
        for (int mi = 0; mi < 4; ++mi) {
          float ss = ssq[mi];
          ss += __shfl_xor(ss, 16, 64);
          ss += __shfl_xor(ss, 32, 64);
          if (lg == 0) {
            const float ci = ss * INVT;
            scv[w * 64 + mi * 16 + lr] = ci;
            if (colb == 0) stf(CV + rowbase + mi * 16 + lr, ci);  // publish once per row
          }
        }
      }
      #pragma unroll
      for (int mi = 0; mi < 4; ++mi) {
        #pragma unroll
        for (int rr = 0; rr < 4; ++rr) {
          const int row = rowbase + mi * 16 + lg * 4 + rr;
          const float crow = scv[w * 64 + mi * 16 + lg * 4 + rr];
          float vm = -3.4e38f, es = 0.f;
          #pragma unroll
          for (int n = 0; n < 4; ++n) {
            const int col = colb + tile * 64 + n * 16 + lr;
            const float v = acc[mi][n][rr] * INVT;
            vm = fmaxf(vm, v);
            const float e0 = __expf(v - crow);
            es += (col == row) ? 0.f : e0;  // exclude diagonal from expsum
          }
          #pragma unroll
          for (int off = 1; off < 16; off <<= 1) {
            vm = fmaxf(vm, __shfl_xor(vm, off, 16));
            es += __shfl_xor(es, off, 16);
          }
          if (lr == 0) {
            atomicMax(MP + row, ordf(vm));
            atomicAdd(EP + row, es);
          }
        }
      }
    }
  }

  // ---- phase 1b: prep tail jobs (Wt one-hot sums, label counts) ----
  __syncthreads();  // smem reuse guard
  if (bid < 160) {
    // Wt[5l+v][d] += F[j][d] over a 512-j block, reg accumulate + 5 atomics
    int* slab = (int*)smem;
    const int ll = bid >> 3, jblk = bid & 7;
    const int j0 = jblk * 512;
    slab[t] = lab[(j0 + t) * 20 + ll];
    __syncthreads();
    const int d = t & 255, half = t >> 8;
    const int base = half * 256;
    float a0 = 0, a1 = 0, a2 = 0, a3 = 0, a4 = 0;
    #pragma unroll 16
    for (int jj = 0; jj < 256; ++jj) {
      const int v = slab[base + jj];
      const float x = F[(size_t)(j0 + base + jj) * 256 + d];
      a0 += (v == 0) ? x : 0.f;
      a1 += (v == 1) ? x : 0.f;
      a2 += (v == 2) ? x : 0.f;
      a3 += (v == 3) ? x : 0.f;
      a4 += (v == 4) ? x : 0.f;
    }
    float* Wt = (float*)(ws + WT_OFF);
    atomicAdd(Wt + (ll * 5 + 0) * 256 + d, a0);
    atomicAdd(Wt + (ll * 5 + 1) * 256 + d, a1);
    atomicAdd(Wt + (ll * 5 + 2) * 256 + d, a2);
    atomicAdd(Wt + (ll * 5 + 3) * 256 + d, a3);
    atomicAdd(Wt + (ll * 5 + 4) * 256 + d, a4);
  } else if (bid < 180) {
    // counts[l][v]
    int* sc = (int*)smem;  // [8][5]
    const int ll = bid - 160;
    int c0 = 0, c1 = 0, c2 = 0, c3 = 0, c4 = 0;
    for (int j = t; j < 4096; j += 512) {
      int v = lab[j * 20 + ll];
      c0 += (v == 0); c1 += (v == 1); c2 += (v == 2); c3 += (v == 3); c4 += (v == 4);
    }
    #pragma unroll
    for (int off = 1; off < 64; off <<= 1) {
      c0 += __shfl_xor(c0, off, 64); c1 += __shfl_xor(c1, off, 64);
      c2 += __shfl_xor(c2, off, 64); c3 += __shfl_xor(c3, off, 64);
      c4 += __shfl_xor(c4, off, 64);
    }
    const int w = t >> 6;
    if ((t & 63) == 0) { sc[w*5+0] = c0; sc[w*5+1] = c1; sc[w*5+2] = c2; sc[w*5+3] = c3; sc[w*5+4] = c4; }
    __syncthreads();
    if (t < 5) {
      int s5 = 0;
      #pragma unroll
      for (int ww = 0; ww < 8; ++ww) s5 += sc[ww * 5 + t];
      stu((unsigned*)(ws + CNT_OFF) + ll * 5 + t, (unsigned)s5);
    }
  }
  gsync(ctr, 512);

  // ---- phase 2: per-row val = lp + m bucketed into (l,v) accumulators ----
  {
    float* sLPM = (float*)smem;         // [100]
    float* sC = (float*)smem + 128;     // [100]
    if (t < 100) { sLPM[t] = 0.f; sC[t] = 0.f; }
    __syncthreads();
    if (t < 16) {
      const int i = bid * 16 + t;
      const float m = ordinv(ldu((const unsigned*)(ws + MP_OFF) + i));
      const float e = ldf((const float*)(ws + EP_OFF) + i);
      const float c = ldf((const float*)(ws + CV_OFF) + i);
      const float val = logf(e * __expf(c - m) + 1e-20f) + m;
      #pragma unroll
      for (int ll = 0; ll < 20; ++ll) {
        const int v = lab[i * 20 + ll];
        atomicAdd(&sLPM[ll * 5 + v], val);
        atomicAdd(&sC[ll * 5 + v], c);
      }
    }
    __syncthreads();
    float* ACC = (float*)(ws + ACC_OFF);
    if (t < 100) {
      atomicAdd(ACC + t, sLPM[t]);
      atomicAdd(ACC + 100 + t, sC[t]);
    }
  }
  gsync(ctr, 768);

  // ---- phase 3: block 0 computes ||Wt||^2 and the final scalar ----
  if (bid == 0) {
    float* wn2 = (float*)(smem + 1024);  // [100]
    const int w = t >> 6, l = t & 63;
    const float* Wt = (const float*)(ws + WT_OFF);
    for (int row = w; row < 100; row += 8) {
      const float* p = Wt + row * 256 + l * 4;
      float q0 = ldf(p), q1 = ldf(p + 1), q2 = ldf(p + 2), q3 = ldf(p + 3);
      float s = q0 * q0 + q1 * q1 + q2 * q2 + q3 * q3;
      #pragma unroll
      for (int off = 1; off < 64; off <<= 1) s += __shfl_xor(s, off, 64);
      if (l == 0) wn2[row] = s;
    }
    __syncthreads();
    if (t == 0) {
      const float* ACC = (const float*)(ws + ACC_OFF);
      const int* cnts = (const int*)(ws + CNT_OFF);
      float loss = 0.f;
      for (int ll = 0; ll < 20; ++ll) {
        float ls = 0.f, singles = 0.f;
        for (int v = 0; v < 5; ++v) {
          const int idx = ll * 5 + v;
          const int cnt = ldi(cnts + idx);
          if (cnt >= 2) {
            const float Ls = ldf(ACC + idx);
            const float Cs = ldf(ACC + 100 + idx);
            ls += Ls - (wn2[idx] * INVT - Cs) / (float)(cnt - 1);
          } else if (cnt == 1) {
            singles += 1.f;
          }
        }
        loss += ls / (4096.f - singles);
      }
      out[0] = loss * 0.05f;
    }
  }
}

extern "C" void kernel_launch(void* const* d_in, const int* in_sizes, int n_in,
                              void* d_out, int out_size, void* d_ws, size_t ws_size,
                              hipStream_t stream) {
  const float* F = (const float*)d_in[0];
  const int* lab = (const int*)d_in[1];
  unsigned char* ws = (unsigned char*)d_ws;
  float* out = (float*)d_out;
  k_mega<<<256, 512, 0, stream>>>(F, lab, ws, out);  // single dispatch
}

// Round 11
// 175.683 us; speedup vs baseline: 2.0774x; 2.0774x over previous
//
#include <hip/hip_runtime.h>

// SupConLoss, B=4096 D=256 L=20, T=0.07.
// 3 dispatches: memset | k_fused{F@F^T row-reduce GEMM + CV publish, Wt one-hot build}
//             | k_final{O(B*L) bucketing + factorized scalar}.
// Factorization: for bucket (l,v) with count n>=2 (cnt=n-1 positives per anchor):
//   sum_i lv_i = sum_i (lp_i + m_i) - (INVT*||Wt[l,v]||^2 - sum_i c_i) / cnt
// where Wt = sum_j F_j onehot(lab_j). Per-row max via ordered-uint atomicMax,
// stabilized expsum via atomicAdd (underflows to 0 exactly like the fp32 reference).

#define INVT 14.285714285714286f

// ws layout (bytes). memset spans [0x10000, 0x32000).
#define WT_OFF   0x010000u  // f32 [100][256] atomic-accumulated (memset 0)
#define ACC_OFF  0x029000u  // f32 LPM[100], C[100], CNT[100], u32 done @+1200 (memset 0)
#define MP_OFF   0x02A000u  // u32 [4096] ordered-float row max (memset 0)
#define EP_OFF   0x02E000u  // f32 [4096] row expsum (memset 0)
#define CV_OFF   0x032000u  // f32 [4096] c_i (S units), written by colb==0 GEMM blocks

typedef __bf16 bf16x8 __attribute__((ext_vector_type(8)));
typedef float f32x4 __attribute__((ext_vector_type(4)));

struct __align__(16) U4 { unsigned int x, y, z, w; };

__device__ __forceinline__ U4 pack8(float4 a, float4 b) {
  bf16x8 v;
  v[0] = (__bf16)a.x; v[1] = (__bf16)a.y; v[2] = (__bf16)a.z; v[3] = (__bf16)a.w;
  v[4] = (__bf16)b.x; v[5] = (__bf16)b.y; v[6] = (__bf16)b.z; v[7] = (__bf16)b.w;
  return __builtin_bit_cast(U4, v);  // v_cvt_pk_bf16_f32 pairs
}

__device__ __forceinline__ unsigned int ordf(float x) {  // monotone float->uint
  unsigned int u = __float_as_uint(x);
  return (u & 0x80000000u) ? ~u : (u | 0x80000000u);
}
__device__ __forceinline__ float ordinv(unsigned int o) {
  return __uint_as_float((o & 0x80000000u) ? (o & 0x7FFFFFFFu) : ~o);
}

// ---- fused: F@F^T row-reduce GEMM (0..255) | Wt build (256..415) ----
__global__ __launch_bounds__(512, 2) void k_fused(const float* __restrict__ F,
                                                  const int* __restrict__ lab,
                                                  unsigned char* __restrict__ ws) {
  __shared__ unsigned char smem[67584];  // 64K B-panel | 2K scv
  const int bid = blockIdx.x, t = threadIdx.x;
  if (bid < 256) {
    const int w = t >> 6, l = t & 63;
    const int lr = l & 15, lg = l >> 4;
    // 2-D XCD partition (perf-only)
    const int r = bid & 7, s = bid >> 3;
    const int bm = ((r & 3) << 1) | (s & 1);
    const int bn = ((r >> 2) << 4) | (s >> 1);
    const int rowbase = bm * 512 + w * 64;
    const int colb = bn * 128;
    // stage B-panel rows [colb..colb+128): fp32 -> bf16 -> swizzled LDS
    {
      const int srow = t >> 2, q = t & 3;
      const float* src = F + (size_t)(colb + srow) * 256 + q * 64;
      #pragma unroll
      for (int i = 0; i < 8; ++i) {
        float4 f0 = *(const float4*)(src + i * 8);
        float4 f1 = *(const float4*)(src + i * 8 + 4);
        const int kb = q * 128 + i * 16;
        *(U4*)(smem + srow * 512 + (kb ^ ((srow & 7) << 4))) = pack8(f0, f1);
      }
    }
    __syncthreads();
    unsigned int* MP = (unsigned int*)(ws + MP_OFF);
    float* EP = (float*)(ws + EP_OFF);
    float* CV = (float*)(ws + CV_OFF);
    float* scv = (float*)(smem + 65536);       // [8 waves][64 rows] c_i (S units)
    const float* arow0 = F + (size_t)(rowbase + lr) * 256 + lg * 8;
    float ssq[4] = {0.f, 0.f, 0.f, 0.f};
    #pragma unroll 1
    for (int tile = 0; tile < 2; ++tile) {
      f32x4 acc[4][4] = {};
      #pragma unroll 1
      for (int kk = 0; kk < 8; ++kk) {
        bf16x8 afr[4];
        #pragma unroll
        for (int mi = 0; mi < 4; ++mi) {
          const float* ap = arow0 + mi * 16 * 256 + kk * 32;
          float4 a0 = *(const float4*)(ap);
          float4 a1 = *(const float4*)(ap + 4);
          if (tile == 0)
            ssq[mi] += a0.x * a0.x + a0.y * a0.y + a0.z * a0.z + a0.w * a0.w
                     + a1.x * a1.x + a1.y * a1.y + a1.z * a1.z + a1.w * a1.w;
          afr[mi] = __builtin_bit_cast(bf16x8, pack8(a0, a1));
        }
        bf16x8 bfr[4];
        #pragma unroll
        for (int n = 0; n < 4; ++n) {
          const int brow = tile * 64 + n * 16 + lr;
          const int kb = kk * 64 + lg * 16;
          bfr[n] = __builtin_bit_cast(bf16x8,
              *(const U4*)(smem + brow * 512 + (kb ^ ((brow & 7) << 4))));
        }
        #pragma unroll
        for (int mi = 0; mi < 4; ++mi)
          #pragma unroll
          for (int n = 0; n < 4; ++n)
            acc[mi][n] = __builtin_amdgcn_mfma_f32_16x16x32_bf16(afr[mi], bfr[n], acc[mi][n], 0, 0, 0);
      }
      if (tile == 0) {
        // finish per-row sumsq: lanes {lr, lr+16, lr+32, lr+48} hold partials of row mi*16+lr
        #pragma unroll
        for (int mi = 0; mi < 4; ++mi) {
          float ss = ssq[mi];
          ss += __shfl_xor(ss, 16, 64);
          ss += __shfl_xor(ss, 32, 64);
          if (lg == 0) {
            const float ci = ss * INVT;
            scv[w * 64 + mi * 16 + lr] = ci;
            if (colb == 0) CV[rowbase + mi * 16 + lr] = ci;  // publish once per row
          }
        }
      }
      #pragma unroll
      for (int mi = 0; mi < 4; ++mi) {
        #pragma unroll
        for (int rr = 0; rr < 4; ++rr) {
          const int row = rowbase + mi * 16 + lg * 4 + rr;
          const float crow = scv[w * 64 + mi * 16 + lg * 4 + rr];
          float vm = -3.4e38f, es = 0.f;
          #pragma unroll
          for (int n = 0; n < 4; ++n) {
            const int col = colb + tile * 64 + n * 16 + lr;
            const float v = acc[mi][n][rr] * INVT;
            vm = fmaxf(vm, v);
            const float e0 = __expf(v - crow);
            es += (col == row) ? 0.f : e0;  // exclude diagonal from expsum
          }
          #pragma unroll
          for (int off = 1; off < 16; off <<= 1) {
            vm = fmaxf(vm, __shfl_xor(vm, off, 16));
            es += __shfl_xor(es, off, 16);
          }
          if (lr == 0) {
            atomicMax(MP + row, ordf(vm));
            atomicAdd(EP + row, es);
          }
        }
      }
    }
  } else {
    // Wt[5l+v][d] += F[j][d] over a 512-j block, reg accumulate + 5 atomics
    int* slab = (int*)smem;
    const int idx = bid - 256;           // 0..159
    const int ll = idx >> 3, jblk = idx & 7;
    const int j0 = jblk * 512;
    slab[t] = lab[(j0 + t) * 20 + ll];
    __syncthreads();
    const int d = t & 255, half = t >> 8;
    const int base = half * 256;
    float a0 = 0, a1 = 0, a2 = 0, a3 = 0, a4 = 0;
    #pragma unroll 16
    for (int jj = 0; jj < 256; ++jj) {
      const int v = slab[base + jj];
      const float x = F[(size_t)(j0 + base + jj) * 256 + d];
      a0 += (v == 0) ? x : 0.f;
      a1 += (v == 1) ? x : 0.f;
      a2 += (v == 2) ? x : 0.f;
      a3 += (v == 3) ? x : 0.f;
      a4 += (v == 4) ? x : 0.f;
    }
    float* Wt = (float*)(ws + WT_OFF);
    atomicAdd(Wt + (ll * 5 + 0) * 256 + d, a0);
    atomicAdd(Wt + (ll * 5 + 1) * 256 + d, a1);
    atomicAdd(Wt + (ll * 5 + 2) * 256 + d, a2);
    atomicAdd(Wt + (ll * 5 + 3) * 256 + d, a3);
    atomicAdd(Wt + (ll * 5 + 4) * 256 + d, a4);
  }
}

// ---- final: per-row (lp+m, c, 1) bucketing (O(B*L)) + last-block norms & scalar ----
__global__ __launch_bounds__(256) void k_final(const int* __restrict__ lab,
                                               unsigned char* __restrict__ ws,
                                               float* __restrict__ out) {
  __shared__ float sB[300];   // LPM[100] | C[100] | CNT[100]
  __shared__ float wn2[100];
  __shared__ int isLast;
  const int t = threadIdx.x;
  for (int k = t; k < 300; k += 256) sB[k] = 0.f;
  __syncthreads();
  const int i = blockIdx.x * 256 + t;
  const float m = ordinv(((const unsigned int*)(ws + MP_OFF))[i]);
  const float e = ((const float*)(ws + EP_OFF))[i];
  const float c = ((const float*)(ws + CV_OFF))[i];
  const float val = logf(e * __expf(c - m) + 1e-20f) + m;
  #pragma unroll
  for (int ll = 0; ll < 20; ++ll) {
    const int v = lab[i * 20 + ll];
    atomicAdd(&sB[ll * 5 + v], val);
    atomicAdd(&sB[100 + ll * 5 + v], c);
    atomicAdd(&sB[200 + ll * 5 + v], 1.f);
  }
  __syncthreads();
  float* ACC = (float*)(ws + ACC_OFF);
  for (int k = t; k < 300; k += 256) atomicAdd(ACC + k, sB[k]);
  __syncthreads();
  if (t == 0) {
    __threadfence();
    unsigned int done = atomicAdd((unsigned int*)(ws + ACC_OFF + 1200), 1u);
    isLast = (done == 15);
  }
  __syncthreads();
  if (isLast) {
    // ||Wt[lv]||^2: wave-per-row (4 waves)
    const int w = t >> 6, l = t & 63;
    const float* Wt = (const float*)(ws + WT_OFF);
    for (int row = w; row < 100; row += 4) {
      const float4 q = *(const float4*)(Wt + row * 256 + l * 4);
      float s = q.x * q.x + q.y * q.y + q.z * q.z + q.w * q.w;
      #pragma unroll
      for (int off = 1; off < 64; off <<= 1) s += __shfl_xor(s, off, 64);
      if (l == 0) wn2[row] = s;
    }
    __syncthreads();
    if (t == 0) {
      float loss = 0.f;
      for (int ll = 0; ll < 20; ++ll) {
        float ls = 0.f, singles = 0.f;
        for (int v = 0; v < 5; ++v) {
          const int idx = ll * 5 + v;
          const int cnt = (int)(__hip_atomic_load(ACC + 200 + idx, __ATOMIC_RELAXED,
                                                  __HIP_MEMORY_SCOPE_AGENT) + 0.5f);
          if (cnt >= 2) {
            const float Ls = __hip_atomic_load(ACC + idx, __ATOMIC_RELAXED, __HIP_MEMORY_SCOPE_AGENT);
            const float Cs = __hip_atomic_load(ACC + 100 + idx, __ATOMIC_RELAXED, __HIP_MEMORY_SCOPE_AGENT);
            ls += Ls - (wn2[idx] * INVT - Cs) / (float)(cnt - 1);
          } else if (cnt == 1) {
            singles += 1.f;
          }
        }
        loss += ls / (4096.f - singles);
      }
      out[0] = loss * 0.05f;
    }
  }
}

extern "C" void kernel_launch(void* const* d_in, const int* in_sizes, int n_in,
                              void* d_out, int out_size, void* d_ws, size_t ws_size,
                              hipStream_t stream) {
  const float* F = (const float*)d_in[0];
  const int* lab = (const int*)d_in[1];
  unsigned char* ws = (unsigned char*)d_ws;
  float* out = (float*)d_out;
  hipMemsetAsync(ws + WT_OFF, 0, 0x22000, stream);   // Wt + ACC + MP + EP
  k_fused<<<416, 512, 0, stream>>>(F, lab, ws);      // 256 GEMM + 160 Wt
  k_final<<<16, 256, 0, stream>>>(lab, ws, out);
}

// Round 12
// 164.196 us; speedup vs baseline: 2.2228x; 1.0700x over previous
//
#include <hip/hip_runtime.h>

// SupConLoss, B=4096 D=256 L=20, T=0.07 — 2 dispatches, no memset.
// k_fused: F@F^T row-reduce GEMM (dense MPT/EPT per-64col partials + CV publish)
//          + Wt one-hot chunk partials WP[8][100][256] (dense, init-free).
// k_final: per-row m/e reduce + lp bucketing into per-(l,v) partials (dense ACCP),
//          parallel wn2 norms; block 15 waits on MAGIC flags, computes scalar in parallel.
// Factorization: bucket (l,v) with n members: sum_i masked_mean_i
//   = (INVT*||Wt[l,v]||^2 - sum_i c_i)/(n-1);  loss_l = (sum lv) / (4096 - singles_l).

#define INVT 14.285714285714286f
#define MAGIC 0x5EC7C0DEu

// ws layout (bytes) — all buffers dense-written, no init required.
#define WP_OFF   0x010000u  // f32 [8][100][256] Wt chunk partials
#define MPT_OFF  0x100000u  // f32 [64][4096] per-64col row max
#define EPT_OFF  0x200000u  // f32 [64][4096] per-64col stabilized expsum
#define CV_OFF   0x300000u  // f32 [4096] c_i (S units)
#define WN_OFF   0x304000u  // f32 [100] ||Wt row||^2
#define ACCP_OFF 0x305000u  // f32 [16][300] per-block bucket partials (LPM|C|CNT)
#define DONE_OFF 0x310000u  // u32 [16] MAGIC completion flags

typedef __bf16 bf16x8 __attribute__((ext_vector_type(8)));
typedef float f32x4 __attribute__((ext_vector_type(4)));

struct __align__(16) U4 { unsigned int x, y, z, w; };

__device__ __forceinline__ U4 pack8(float4 a, float4 b) {
  bf16x8 v;
  v[0] = (__bf16)a.x; v[1] = (__bf16)a.y; v[2] = (__bf16)a.z; v[3] = (__bf16)a.w;
  v[4] = (__bf16)b.x; v[5] = (__bf16)b.y; v[6] = (__bf16)b.z; v[7] = (__bf16)b.w;
  return __builtin_bit_cast(U4, v);
}

__device__ __forceinline__ void stf(float* p, float v) {
  __hip_atomic_store(p, v, __ATOMIC_RELAXED, __HIP_MEMORY_SCOPE_AGENT);
}
__device__ __forceinline__ float ldf(const float* p) {
  return __hip_atomic_load(p, __ATOMIC_RELAXED, __HIP_MEMORY_SCOPE_AGENT);
}

// ---- fused: F@F^T row-reduce GEMM (0..255) | Wt chunk partials (256..415) ----
__global__ __launch_bounds__(512, 2) void k_fused(const float* __restrict__ F,
                                                  const int* __restrict__ lab,
                                                  unsigned char* __restrict__ ws) {
  __shared__ unsigned char smem[75776];  // 64K B-panel | 8K scr | 2K scv
  const int bid = blockIdx.x, t = threadIdx.x;
  if (bid < 256) {
    const int w = t >> 6, l = t & 63;
    const int lr = l & 15, lg = l >> 4;
    // 2-D XCD partition (perf-only)
    const int r = bid & 7, s = bid >> 3;
    const int bm = ((r & 3) << 1) | (s & 1);
    const int bn = ((r >> 2) << 4) | (s >> 1);
    const int rowbase = bm * 512 + w * 64;
    const int colb = bn * 128;
    // stage B-panel rows [colb..colb+128): fp32 -> bf16 -> swizzled LDS
    {
      const int srow = t >> 2, q = t & 3;
      const float* src = F + (size_t)(colb + srow) * 256 + q * 64;
      #pragma unroll
      for (int i = 0; i < 8; ++i) {
        float4 f0 = *(const float4*)(src + i * 8);
        float4 f1 = *(const float4*)(src + i * 8 + 4);
        const int kb = q * 128 + i * 16;
        *(U4*)(smem + srow * 512 + (kb ^ ((srow & 7) << 4))) = pack8(f0, f1);
      }
    }
    __syncthreads();
    float* MPT = (float*)(ws + MPT_OFF);
    float* EPT = (float*)(ws + EPT_OFF);
    float* CV = (float*)(ws + CV_OFF);
    float* scv = (float*)(smem + 73728);       // [8 waves][64 rows] c_i (S units)
    const float* arow0 = F + (size_t)(rowbase + lr) * 256 + lg * 8;
    float ssq[4] = {0.f, 0.f, 0.f, 0.f};
    #pragma unroll 1
    for (int tile = 0; tile < 2; ++tile) {
      f32x4 acc[4][4] = {};
      #pragma unroll 1
      for (int kk = 0; kk < 8; ++kk) {
        bf16x8 afr[4];
        #pragma unroll
        for (int mi = 0; mi < 4; ++mi) {
          const float* ap = arow0 + mi * 16 * 256 + kk * 32;
          float4 a0 = *(const float4*)(ap);
          float4 a1 = *(const float4*)(ap + 4);
          if (tile == 0)
            ssq[mi] += a0.x * a0.x + a0.y * a0.y + a0.z * a0.z + a0.w * a0.w
                     + a1.x * a1.x + a1.y * a1.y + a1.z * a1.z + a1.w * a1.w;
          afr[mi] = __builtin_bit_cast(bf16x8, pack8(a0, a1));
        }
        bf16x8 bfr[4];
        #pragma unroll
        for (int n = 0; n < 4; ++n) {
          const int brow = tile * 64 + n * 16 + lr;
          const int kb = kk * 64 + lg * 16;
          bfr[n] = __builtin_bit_cast(bf16x8,
              *(const U4*)(smem + brow * 512 + (kb ^ ((brow & 7) << 4))));
        }
        #pragma unroll
        for (int mi = 0; mi < 4; ++mi)
          #pragma unroll
          for (int n = 0; n < 4; ++n)
            acc[mi][n] = __builtin_amdgcn_mfma_f32_16x16x32_bf16(afr[mi], bfr[n], acc[mi][n], 0, 0, 0);
      }
      if (tile == 0) {
        // finish per-row sumsq: lanes {lr, lr+16, lr+32, lr+48} hold partials of row mi*16+lr
        #pragma unroll
        for (int mi = 0; mi < 4; ++mi) {
          float ss = ssq[mi];
          ss += __shfl_xor(ss, 16, 64);
          ss += __shfl_xor(ss, 32, 64);
          if (lg == 0) {
            const float ci = ss * INVT;
            scv[w * 64 + mi * 16 + lr] = ci;
            if (colb == 0) CV[rowbase + mi * 16 + lr] = ci;  // publish once per row
          }
        }
      }
      float2* scr = (float2*)(smem + 65536 + (w * 2 + tile) * 512);
      #pragma unroll
      for (int mi = 0; mi < 4; ++mi) {
        #pragma unroll
        for (int rr = 0; rr < 4; ++rr) {
          const int row = rowbase + mi * 16 + lg * 4 + rr;
          const float crow = scv[w * 64 + mi * 16 + lg * 4 + rr];
          float vm = -3.4e38f, es = 0.f;
          #pragma unroll
          for (int n = 0; n < 4; ++n) {
            const int col = colb + tile * 64 + n * 16 + lr;
            const float v = acc[mi][n][rr] * INVT;
            vm = fmaxf(vm, v);
            const float e0 = __expf(v - crow);
            es += (col == row) ? 0.f : e0;  // exclude diagonal from expsum
          }
          #pragma unroll
          for (int off = 1; off < 16; off <<= 1) {
            vm = fmaxf(vm, __shfl_xor(vm, off, 16));
            es += __shfl_xor(es, off, 16);
          }
          if (lr == 0) scr[mi * 16 + lg * 4 + rr] = make_float2(vm, es);
        }
      }
      // dense coalesced stores (wave-private scratch, wave-synchronous)
      const float2 v2 = scr[l];
      const int c2 = (colb >> 6) + tile;   // 0..63
      MPT[c2 * 4096 + rowbase + l] = v2.x;
      EPT[c2 * 4096 + rowbase + l] = v2.y;
    }
  } else {
    // WP[jblk][5l+v][d] = partial sums over a 512-j block (dense, init-free)
    int* slab = (int*)smem;
    const int idx = bid - 256;           // 0..159
    const int ll = idx >> 3, jblk = idx & 7;
    const int j0 = jblk * 512;
    slab[t] = lab[(j0 + t) * 20 + ll];
    __syncthreads();
    const int d = t & 255, half = t >> 8;
    const int base = half * 256;
    float a0 = 0, a1 = 0, a2 = 0, a3 = 0, a4 = 0;
    #pragma unroll 16
    for (int jj = 0; jj < 256; ++jj) {
      const int v = slab[base + jj];
      const float x = F[(size_t)(j0 + base + jj) * 256 + d];
      a0 += (v == 0) ? x : 0.f;
      a1 += (v == 1) ? x : 0.f;
      a2 += (v == 2) ? x : 0.f;
      a3 += (v == 3) ? x : 0.f;
      a4 += (v == 4) ? x : 0.f;
    }
    // two halves write disjoint? No — same rows; combine via LDS then one store.
    float* red = (float*)(smem + 4096);  // [2][5][256]
    red[(half * 5 + 0) * 256 + d] = a0;
    red[(half * 5 + 1) * 256 + d] = a1;
    red[(half * 5 + 2) * 256 + d] = a2;
    red[(half * 5 + 3) * 256 + d] = a3;
    red[(half * 5 + 4) * 256 + d] = a4;
    __syncthreads();
    float* WP = (float*)(ws + WP_OFF);
    if (half == 0) {
      #pragma unroll
      for (int v = 0; v < 5; ++v)
        WP[(size_t)(jblk * 100 + ll * 5 + v) * 256 + d] =
            red[v * 256 + d] + red[(5 + v) * 256 + d];
    }
  }
}

// ---- final: parallel wn2 | per-row bucketing | block-15 parallel scalar ----
__global__ __launch_bounds__(256) void k_final(const int* __restrict__ lab,
                                               unsigned char* __restrict__ ws,
                                               float* __restrict__ out) {
  __shared__ float sB[300];
  __shared__ float SB[300], cB[100], cS[100], part[20];
  const int bid = blockIdx.x, t = threadIdx.x, w = t >> 6, l = t & 63;
  const float* WP = (const float*)(ws + WP_OFF);
  // phase A: wn2 rows r = bid + 16*(w + 4j): wave-per-row over 8 chunks
  for (int r = bid + 16 * w; r < 100; r += 64) {
    float4 q = make_float4(0.f, 0.f, 0.f, 0.f);
    #pragma unroll
    for (int c = 0; c < 8; ++c) {
      const float4 p = *(const float4*)(WP + (size_t)(c * 100 + r) * 256 + l * 4);
      q.x += p.x; q.y += p.y; q.z += p.z; q.w += p.w;
    }
    float s = q.x * q.x + q.y * q.y + q.z * q.z + q.w * q.w;
    #pragma unroll
    for (int off = 1; off < 64; off <<= 1) s += __shfl_xor(s, off, 64);
    if (l == 0) stf((float*)(ws + WN_OFF) + r, s);
  }
  // phase B: per-row reduce + bucketing
  for (int k = t; k < 300; k += 256) sB[k] = 0.f;
  __syncthreads();
  const int i = bid * 256 + t;
  const float* MPT = (const float*)(ws + MPT_OFF);
  const float* EPT = (const float*)(ws + EPT_OFF);
  float m = -3.4e38f, e = 0.f;
  #pragma unroll
  for (int c2 = 0; c2 < 64; ++c2) {
    m = fmaxf(m, MPT[c2 * 4096 + i]);   // coalesced
    e += EPT[c2 * 4096 + i];
  }
  const float c = ((const float*)(ws + CV_OFF))[i];
  const float val = logf(e * __expf(c - m) + 1e-20f) + m;
  #pragma unroll
  for (int ll = 0; ll < 20; ++ll) {
    const int v = lab[i * 20 + ll];
    atomicAdd(&sB[ll * 5 + v], val);
    atomicAdd(&sB[100 + ll * 5 + v], c);
    atomicAdd(&sB[200 + ll * 5 + v], 1.f);
  }
  __syncthreads();
  float* ACCP = (float*)(ws + ACCP_OFF);
  for (int k = t; k < 300; k += 256) stf(ACCP + bid * 300 + k, sB[k]);
  __threadfence();
  __syncthreads();
  if (t == 0)
    __hip_atomic_store((unsigned*)(ws + DONE_OFF) + bid, MAGIC,
                       __ATOMIC_RELEASE, __HIP_MEMORY_SCOPE_AGENT);
  // phase C: block 15 waits for all flags, computes scalar in parallel
  if (bid != 15) return;
  if (t < 16) {
    while (__hip_atomic_load((const unsigned*)(ws + DONE_OFF) + t,
                             __ATOMIC_ACQUIRE, __HIP_MEMORY_SCOPE_AGENT) != MAGIC)
      __builtin_amdgcn_s_sleep(8);
  }
  __syncthreads();
  for (int k = t; k < 300; k += 256) {
    float s = 0.f;
    #pragma unroll
    for (int b = 0; b < 16; ++b) s += ldf(ACCP + b * 300 + k);
    SB[k] = s;
  }
  __syncthreads();
  if (t < 100) {
    const int cnt = (int)(SB[200 + t] + 0.5f);
    float contr = 0.f, sg = 0.f;
    if (cnt >= 2) {
      const float w2 = ldf((const float*)(ws + WN_OFF) + t);
      contr = SB[t] - (w2 * INVT - SB[100 + t]) / (float)(cnt - 1);
    } else if (cnt == 1) {
      sg = 1.f;
    }
    cB[t] = contr; cS[t] = sg;
  }
  __syncthreads();
  if (t < 20) {
    float ls = 0.f, sgs = 0.f;
    #pragma unroll
    for (int v = 0; v < 5; ++v) { ls += cB[t * 5 + v]; sgs += cS[t * 5 + v]; }
    part[t] = ls / (4096.f - sgs);
  }
  __syncthreads();
  if (t == 0) {
    float loss = 0.f;
    #pragma unroll
    for (int ll = 0; ll < 20; ++ll) loss += part[ll];
    out[0] = loss * 0.05f;
  }
}

extern "C" void kernel_launch(void* const* d_in, const int* in_sizes, int n_in,
                              void* d_out, int out_size, void* d_ws, size_t ws_size,
                              hipStream_t stream) {
  const float* F = (const float*)d_in[0];
  const int* lab = (const int*)d_in[1];
  unsigned char* ws = (unsigned char*)d_ws;
  float* out = (float*)d_out;
  k_fused<<<416, 512, 0, stream>>>(F, lab, ws);   // 256 GEMM + 160 Wt partials
  k_final<<<16, 256, 0, stream>>>(lab, ws, out);  // bucketing + parallel scalar
}